// Round 9
// baseline (592.731 us; speedup 1.0000x reference)
//
#include <hip/hip_runtime.h>

typedef _Float16 HALF;
typedef _Float16 f16x8 __attribute__((ext_vector_type(8)));
typedef float f32x4 __attribute__((ext_vector_type(4)));
typedef int i32x4 __attribute__((ext_vector_type(4)));

__host__ __device__ inline int padded_kp(int CI)
{
    int nch  = (27 * CI + 31) / 32;
    int nchp = ((nch + 3) / 4) * 4;      // CKC = 4 everywhere
    return nchp * 32;
}

// ---- fused weight conversion: fp32 (27*CI, CO) -> fp16 tiled [KP/32][CO_PAD][32],
// zero padded in co and in k up to a 4-multiple of 32-k tiles.
struct WArgs { const float* W[8]; HALF* dst[8]; };

__global__ void convert_all_w_kernel(WArgs a)
{
    const int CIs[8]  = {64, 64, 64, 64, 32, 32, 16, 16};
    const int COs[8]  = {64, 64, 64, 32, 32, 16, 16, 3};
    const int COPs[8] = {64, 64, 64, 32, 32, 16, 16, 16};
    const int L = blockIdx.y;
    const int CI = CIs[L], CO = COs[L], COP = COPs[L];
    const int K = 27 * CI;
    const int KP = padded_kp(CI);
    const int total = COP * KP;
    for (int i = blockIdx.x * 256 + threadIdx.x; i < total; i += gridDim.x * 256) {
        int jp = i / KP;          // out channel (padded)
        int kp = i - jp * KP;     // k (padded)
        float v = (jp < CO && kp < K) ? a.W[L][(size_t)kp * CO + jp] : 0.f;
        a.dst[L][((size_t)(kp >> 5) * COP + jp) * 32 + (kp & 31)] = (HALF)v;
    }
}

__global__ void convert_x_kernel(const float* __restrict__ x, HALF* __restrict__ xh, int total)
{
    int i = blockIdx.x * 256 + threadIdx.x;
    if (i < total) xh[i] = (HALF)x[i];
}

// ---- conv: shared-gather-stream lockstep blocks.
// Standing evidence (r0-r8): conv64 pinned at 77us iff each wave runs a private
// A-gather stream; removing B/idx VMEM entirely changed nothing. Intrinsic reuse
// (dx-window: consecutive kc steps share ~2/3 of their 64B lines; co-slice waves
// share ALL lines) never lands because 8 waves x private streams = 130KB >> 32KB L1.
// This round: 128 rows/block as 2 row-groups x 2 co-slices (WC=2). Co-slice wave
// pairs issue IDENTICAL gather addresses; per-chunk barriers phase-lock them; the
// live window is ~2 groups x ~16KB ~ L1. Expected A-miss count / ~4-5.
// B double-buffered in LDS ([kcc][lq][co] +1-unit pad: read 2-way), idx in LDS,
// bn fold-in at block prologue (removes the 7 bn_prep dispatches).
// Per-wave body: R2's rolling 2-deep pipeline, NMT=4 -> 4 gathers in flight.
template<int CI, int CO_PAD, int WC, bool FUSED>
__global__ __launch_bounds__(256, 2) void conv_kernel(
    const HALF* __restrict__ h, const int* __restrict__ nbr,
    const HALF* __restrict__ Wt, HALF* __restrict__ yout,
    float* __restrict__ sums, int n,
    const float* __restrict__ psums, const float* __restrict__ pg,
    const float* __restrict__ pb, float pinvn)
{
    constexpr int K      = 27 * CI;
    constexpr int NCH    = (K + 31) / 32;
    constexpr int NCHP   = ((NCH + 3) / 4) * 4;
    constexpr int NCHUNK = NCHP / 4;               // CKC = 4
    constexpr int WR     = 4 / WC;                 // row groups
    constexpr int NJB    = CO_PAD / (16 * WC);     // 16-col tiles per wave
    constexpr int NMT    = 4;                      // 64 rows per group
    constexpr int ROWS   = WR * 64;
    constexpr int LWC    = (WC == 2) ? 1 : 0;
    constexpr int NCB    = (CI >= 64) ? 2 : 1;
    constexpr int LOG2CI = (CI == 64) ? 6 : ((CI == 32) ? 5 : 4);
    constexpr int CP1    = CO_PAD + 1;             // +1 16B-unit pad per lq row
    constexpr int NST    = (16 * CO_PAD) / 256;    // staging 16B-units/thread/chunk
    constexpr int L24CP  = (CO_PAD == 64) ? 8 : ((CO_PAD == 32) ? 7 : 6); // log2(4*CO_PAD)

    __shared__ int   lidx[ROWS * 27];
    __shared__ HALF  bbuf[2][128 * CP1];           // 4 kcc x 4 lq x CP1 units x 8 half
    __shared__ float lscbi[2][64];

    const int wv   = threadIdx.x >> 6;
    const int lane = threadIdx.x & 63;
    const int l15  = lane & 15;
    const int lq   = lane >> 4;
    const int wc   = wv & (WC - 1);                // co-slice
    const int wr   = wv >> LWC;                    // row group
    const int co0  = wc * (16 * NJB);

    // bijective XCD swizzle (8 XCDs): contiguous row ranges share an XCD L2
    int bid = blockIdx.x;
    {
        const int nwg = gridDim.x;
        const int q = nwg >> 3, r = nwg & 7;
        const int xcd = bid & 7, idx = bid >> 3;
        bid = (xcd < r ? xcd * (q + 1) : r * (q + 1) + (xcd - r) * q) + idx;
    }
    const int rowBase  = bid * ROWS;
    const int groupRow = rowBase + wr * 64;        // this wave's 64 rows (shared w/ co-pair)

    // ---- stage neighbor indices (coalesced; OOB rows -> -1)
    for (int i = threadIdx.x; i < ROWS * 27; i += 256) {
        const int r   = i / 27;
        const int row = rowBase + r;
        lidx[i] = (row < n) ? nbr[(size_t)row * 27 + (i - r * 27)] : -1;
    }
    // ---- stage B chunk 0 into padded [kcc][lq][co] layout
    {
#pragma unroll
        for (int j = 0; j < NST; ++j) {
            const int u   = j * 256 + threadIdx.x;
            const int lq2 = u & 3;
            const int co  = (u >> 2) & (CO_PAD - 1);
            const int kcc = u >> L24CP;
            const i32x4 v = *(const i32x4*)(Wt + ((size_t)kcc * (CO_PAD * 32) + co * 32 + lq2 * 8));
            *(i32x4*)(&bbuf[0][(kcc * CP1 * 4 + lq2 * CP1 + co) * 8]) = v;
        }
    }
    // ---- fold producer bn stats -> scale/bias (in-kernel bn_prep; 8-way striped sums)
    if constexpr (FUSED) {
        const int c = threadIdx.x;
        if (c < CI) {
            float s = 0.f, q = 0.f;
#pragma unroll
            for (int k = 0; k < 8; ++k) { s += psums[k * 128 + c]; q += psums[k * 128 + CI + c]; }
            const float mu  = s * pinvn;
            const float var = q * pinvn - mu * mu;
            const float sc  = rsqrtf(var + 1e-3f) * pg[c];
            lscbi[0][c] = sc;
            lscbi[1][c] = pb[c] - mu * sc;
        }
    }

    f32x4 acc[NMT][NJB];
#pragma unroll
    for (int mt = 0; mt < NMT; ++mt)
#pragma unroll
        for (int jb = 0; jb < NJB; ++jb)
#pragma unroll
            for (int r = 0; r < 4; ++r) acc[mt][jb][r] = 0.f;

    int lb[NMT];
#pragma unroll
    for (int mt = 0; mt < NMT; ++mt) lb[mt] = (wr * 64 + mt * 16 + l15) * 27;

    __syncthreads();                               // idx + chunk0 + scbi visible

    // per-lane bn constants from LDS
    f16x8 sc8[NCB], bi8[NCB];
    if constexpr (FUSED) {
#pragma unroll
        for (int cb = 0; cb < NCB; ++cb) {
            const int c0 = cb * 32 + ((lq * 8) & (CI - 1));
#pragma unroll
            for (int j = 0; j < 8; ++j) {
                sc8[cb][j] = (HALF)lscbi[0][c0 + j];
                bi8[cb][j] = (HALF)lscbi[1][c0 + j];
            }
        }
    }

    #define TAPOF(kc_) ((CI == 16) ? (2 * (kc_) + (lq >> 1)) : ((CI == 64) ? ((kc_) >> 1) : (kc_)))
    #define CHOF(kc_)  ((((kc_) * 32) + lq * 8) & (CI - 1))
    #define GIDX(kc_, mt_) ({ const int t_ = TAPOF(kc_); (t_ < 27) ? lidx[lb[mt_] + t_] : -1; })

    // ---- rolling 2-deep A pipeline (R2 body, NMT=4)
    int   ipf[2][NMT];
    f16x8 apf[2][NMT];
#pragma unroll
    for (int p = 0; p < 2; ++p) {
#pragma unroll
        for (int mt = 0; mt < NMT; ++mt) {
            const int idx = GIDX(p, mt);
            ipf[p][mt] = idx;
            apf[p][mt] = *(const f16x8*)(h + ((max(idx, 0) << LOG2CI) + CHOF(p)));
        }
    }

    for (int ch = 0; ch < NCHUNK; ++ch) {
        const HALF* bb = &bbuf[ch & 1][0];

        // stage chunk ch+1 (overlaps with this chunk's compute)
        if (ch + 1 < NCHUNK) {
            const HALF* wsrc = Wt + (size_t)(ch + 1) * 4 * (CO_PAD * 32);
            HALF* wdst = &bbuf[(ch + 1) & 1][0];
#pragma unroll
            for (int j = 0; j < NST; ++j) {
                const int u   = j * 256 + threadIdx.x;
                const int lq2 = u & 3;
                const int co  = (u >> 2) & (CO_PAD - 1);
                const int kcc = u >> L24CP;
                const i32x4 v = *(const i32x4*)(wsrc + ((size_t)kcc * (CO_PAD * 32) + co * 32 + lq2 * 8));
                *(i32x4*)(&wdst[(kcc * CP1 * 4 + lq2 * CP1 + co) * 8]) = v;
            }
        }

#pragma unroll
        for (int kcc = 0; kcc < 4; ++kcc) {
            const int kc  = ch * 4 + kcc;
            const int cur = kcc & 1;               // compile-time (CKC even)
            const int ccb = (NCB == 2) ? (kcc & 1) : 0;

            // B fragments from padded LDS (2-way banks)
            f16x8 b[NJB];
#pragma unroll
            for (int jb = 0; jb < NJB; ++jb)
                b[jb] = *(const f16x8*)(bb + kcc * (CP1 * 32) + lq * (CP1 * 8) + (co0 + jb * 16 + l15) * 8);

            // take current stage
            f16x8 a_use[NMT];
            int   i_use[NMT];
#pragma unroll
            for (int mt = 0; mt < NMT; ++mt) { a_use[mt] = apf[cur][mt]; i_use[mt] = ipf[cur][mt]; }

            // refill with kc+2 (A only; crosses chunk boundary freely)
            if (kc + 2 < NCHP) {
#pragma unroll
                for (int mt = 0; mt < NMT; ++mt) {
                    const int idx = GIDX(kc + 2, mt);
                    ipf[cur][mt] = idx;
                    apf[cur][mt] = *(const f16x8*)(h + ((max(idx, 0) << LOG2CI) + CHOF(kc + 2)));
                }
            }

            // consume
#pragma unroll
            for (int mt = 0; mt < NMT; ++mt) {
                f16x8 a = a_use[mt];
                if constexpr (FUSED) {
                    a = a * sc8[ccb] + bi8[ccb];   // v_pk_fma_f16
#pragma unroll
                    for (int j = 0; j < 8; ++j)
                        a[j] = (a[j] < (HALF)0.f) ? (HALF)0.f : a[j];
                }
                // zero invalid taps AFTER bn so invalid -> exact 0
                const int m = ~(i_use[mt] >> 31);
                i32x4 ai = __builtin_bit_cast(i32x4, a);
                ai.x &= m; ai.y &= m; ai.z &= m; ai.w &= m;
                a = __builtin_bit_cast(f16x8, ai);
#pragma unroll
                for (int jb = 0; jb < NJB; ++jb)
                    acc[mt][jb] = __builtin_amdgcn_mfma_f32_16x16x32_f16(a, b[jb], acc[mt][jb], 0, 0, 0);
            }
        }
        __syncthreads();                           // chunk ch+1 staged; phase re-lock
    }

    #undef TAPOF
    #undef CHOF
    #undef GIDX

    // ---- epilogue: each wave owns (64 rows x 16*NJB cols) - disjoint; striped stats
    // C/D layout: col = lane&15, row = (lane>>4)*4 + reg
    float* sl = sums + (bid & 7) * 128;
#pragma unroll
    for (int jb = 0; jb < NJB; ++jb) {
        const int col = co0 + jb * 16 + l15;
        float s = 0.f, sq = 0.f;
#pragma unroll
        for (int mt = 0; mt < NMT; ++mt) {
            const int rb = groupRow + mt * 16 + lq * 4;
#pragma unroll
            for (int r = 0; r < 4; ++r) {
                if (rb + r < n) {
                    const float v = acc[mt][jb][r];
                    yout[(size_t)(rb + r) * CO_PAD + col] = (HALF)v;
                    s += v;
                    sq += v * v;
                }
            }
        }
        s  += __shfl_xor(s, 16);  s  += __shfl_xor(s, 32);
        sq += __shfl_xor(sq, 16); sq += __shfl_xor(sq, 32);
        if (lane < 16) {
            atomicAdd(&sl[col], s);
            atomicAdd(&sl[CO_PAD + col], sq);
        }
    }
}

// ---- final: normalize (no relu), co=3 out of CO_PAD=16, fp32 output; striped sums
__global__ void bn_out_kernel(const HALF* __restrict__ y, const float* __restrict__ sums,
                              const float* __restrict__ g, const float* __restrict__ b,
                              int n, float invn, float* __restrict__ out)
{
    int i = blockIdx.x * 256 + threadIdx.x;
    if (i >= n * 3) return;
    int row = i / 3;
    int c = i - row * 3;
    float ssum = 0.f, qsum = 0.f;
#pragma unroll
    for (int k2 = 0; k2 < 8; ++k2) {
        ssum += sums[k2 * 128 + c];
        qsum += sums[k2 * 128 + 16 + c];
    }
    float mu  = ssum * invn;
    float var = qsum * invn - mu * mu;
    float sc  = rsqrtf(var + 1e-3f) * g[c];
    out[i] = ((float)y[(size_t)row * 16 + c] - mu) * sc + b[c];
}

extern "C" void kernel_launch(void* const* d_in, const int* in_sizes, int n_in,
                              void* d_out, int out_size, void* d_ws, size_t ws_size,
                              hipStream_t stream)
{
    const int* nbr4  = (const int*)d_in[0];
    const int* inv43 = (const int*)d_in[1];
    const int* nbr3  = (const int*)d_in[2];
    const int* inv32 = (const int*)d_in[3];
    const int* nbr2  = (const int*)d_in[4];
    const int* inv21 = (const int*)d_in[5];
    const int* nbr1  = (const int*)d_in[6];
    const float* x   = (const float*)d_in[7];

    const int n4 = in_sizes[0] / 27;
    const int n3 = in_sizes[1] / 27;
    const int n2 = in_sizes[3] / 27;
    const int n1 = in_sizes[5] / 27;

    // specs: m4,i4,m3,i3,m2,i2,m1,c5
    const int CIs[8]  = {64, 64, 64, 64, 32, 32, 16, 16};
    const int COPs[8] = {64, 64, 64, 32, 32, 16, 16, 16};
    int KPs[8], wtoff[8];
    int wtot = 0;
    for (int s = 0; s < 8; ++s) {
        KPs[s] = padded_kp(CIs[s]);
        wtoff[s] = wtot;
        wtot += COPs[s] * KPs[s];
    }

    char* ws = (char*)d_ws;
    HALF* wt = (HALF*)ws;
    size_t off = ((size_t)wtot * sizeof(HALF) + 255) & ~(size_t)255;
    float* sums = (float*)(ws + off);
    off += 8 * 1024 * sizeof(float);              // 8 layers x 8 stripes x 128 floats
    off = (off + 255) & ~(size_t)255;
    HALF* xh = (HALF*)(ws + off);
    off += ((size_t)n4 * 64 * sizeof(HALF) + 255) & ~(size_t)255;
    size_t bufElems = 0;
    {
        size_t cand[4] = {(size_t)n4 * 64, (size_t)n3 * 64, (size_t)n2 * 32, (size_t)n1 * 16};
        for (int i = 0; i < 4; ++i) if (cand[i] > bufElems) bufElems = cand[i];
    }
    HALF* Y0 = (HALF*)(ws + off);
    off += (bufElems * sizeof(HALF) + 255) & ~(size_t)255;
    HALF* Y1 = (HALF*)(ws + off);

    hipMemsetAsync(sums, 0, 8 * 1024 * sizeof(float), stream);

    WArgs wa;
    for (int s = 0; s < 8; ++s) { wa.W[s] = (const float*)d_in[8 + 3 * s]; wa.dst[s] = wt + wtoff[s]; }
    {
        int maxTotal = 64 * KPs[0];
        dim3 grid((maxTotal + 255) / 256, 8);
        convert_all_w_kernel<<<grid, 256, 0, stream>>>(wa);
    }
    convert_x_kernel<<<(n4 * 64 + 255) / 256, 256, 0, stream>>>(x, xh, n4 * 64);

#define G(s) ((const float*)d_in[9 + 3 * (s)])
#define B(s) ((const float*)d_in[10 + 3 * (s)])
#define SUMS(s) (sums + (s) * 1024)
#define GRIDR(nn, rows) (((nn) + (rows) - 1) / (rows))

    // m4: xh(n4,64) -> Y0 (raw); 128 rows/block
    conv_kernel<64, 64, 2, false><<<GRIDR(n4, 128), 256, 0, stream>>>(
        xh, nbr4, wt + wtoff[0], Y0, SUMS(0), n4, nullptr, nullptr, nullptr, 0.f);
    // i4: norm(m4) fused; Y0(n4) -> Y1(n3)
    conv_kernel<64, 64, 2, true><<<GRIDR(n3, 128), 256, 0, stream>>>(
        Y0, inv43, wt + wtoff[1], Y1, SUMS(1), n3, SUMS(0), G(0), B(0), 1.f / n4);
    // m3: norm(i4) fused; Y1 -> Y0
    conv_kernel<64, 64, 2, true><<<GRIDR(n3, 128), 256, 0, stream>>>(
        Y1, nbr3, wt + wtoff[2], Y0, SUMS(2), n3, SUMS(1), G(1), B(1), 1.f / n3);
    // i3: norm(m3) fused; Y0(n3) -> Y1(n2), co 32
    conv_kernel<64, 32, 2, true><<<GRIDR(n2, 128), 256, 0, stream>>>(
        Y0, inv32, wt + wtoff[3], Y1, SUMS(3), n2, SUMS(2), G(2), B(2), 1.f / n3);
    // m2: norm(i3) fused; Y1 -> Y0
    conv_kernel<32, 32, 2, true><<<GRIDR(n2, 128), 256, 0, stream>>>(
        Y1, nbr2, wt + wtoff[4], Y0, SUMS(4), n2, SUMS(3), G(3), B(3), 1.f / n2);
    // i2: norm(m2) fused; Y0(n2) -> Y1(n1), co 16; 256 rows/block
    conv_kernel<32, 16, 1, true><<<GRIDR(n1, 256), 256, 0, stream>>>(
        Y0, inv21, wt + wtoff[5], Y1, SUMS(5), n1, SUMS(4), G(4), B(4), 1.f / n2);
    // m1: norm(i2) fused; Y1 -> Y0
    conv_kernel<16, 16, 1, true><<<GRIDR(n1, 256), 256, 0, stream>>>(
        Y1, nbr1, wt + wtoff[6], Y0, SUMS(6), n1, SUMS(5), G(5), B(5), 1.f / n1);
    // c5: norm(m1) fused; Y0 -> Y1 (raw), then fp32 out
    conv_kernel<16, 16, 1, true><<<GRIDR(n1, 256), 256, 0, stream>>>(
        Y0, nbr1, wt + wtoff[7], Y1, SUMS(7), n1, SUMS(6), G(6), B(6), 1.f / n1);
    bn_out_kernel<<<(n1 * 3 + 255) / 256, 256, 0, stream>>>(
        Y1, SUMS(7), G(7), B(7), n1, 1.f / n1, (float*)d_out);

#undef G
#undef B
#undef SUMS
#undef GRIDR
}

// Round 10
// 482.771 us; speedup vs baseline: 1.2278x; 1.2278x over previous
//
#include <hip/hip_runtime.h>

typedef _Float16 HALF;
typedef _Float16 f16x8 __attribute__((ext_vector_type(8)));
typedef float f32x4 __attribute__((ext_vector_type(4)));
typedef int i32x4 __attribute__((ext_vector_type(4)));

// ---- fused weight conversion: fp32 (27*CI, CO) -> fp16 tiled [KP/32][CO_PAD][32], zero padded
struct WArgs { const float* W[8]; HALF* dst[8]; };

__global__ void convert_all_w_kernel(WArgs a)
{
    const int CIs[8]  = {64, 64, 64, 64, 32, 32, 16, 16};
    const int COs[8]  = {64, 64, 64, 32, 32, 16, 16, 3};
    const int COPs[8] = {64, 64, 64, 32, 32, 16, 16, 16};
    const int L = blockIdx.y;
    const int CI = CIs[L], CO = COs[L], COP = COPs[L];
    const int K = 27 * CI, KP = (K + 31) & ~31;
    const int total = COP * KP;
    for (int i = blockIdx.x * 256 + threadIdx.x; i < total; i += gridDim.x * 256) {
        int jp = i / KP;          // out channel (padded)
        int kp = i - jp * KP;     // k (padded)
        float v = (jp < CO && kp < K) ? a.W[L][(size_t)kp * CO + jp] : 0.f;
        a.dst[L][((size_t)(kp >> 5) * COP + jp) * 32 + (kp & 31)] = (HALF)v;
    }
}

__global__ void convert_x_kernel(const float* __restrict__ x, HALF* __restrict__ xh, int total)
{
    int i = blockIdx.x * 256 + threadIdx.x;
    if (i < total) xh[i] = (HALF)x[i];
}

// ---- conv: k-split across waves (R6 structure, best@518us) with two changes:
// (1) CI=64 layers iterate per TAP: both 64B halves of each gathered row's 128B
//     line load in ADJACENT instructions (R6 accessed them ~1250 cyc apart ->
//     second half always re-missed). If vL1/L2 fill granularity is 128B this
//     halves the A-miss count - the only resource the 10-round evidence says
//     matters (R8: removing ALL B+idx VMEM changed nothing; misses are the wall).
// (2) bn stats folded to scale/bias in-kernel via LDS (kills 7 bn_prep dispatches).
// Everything else identical to R6: grid n/32, 4-wave k-split, NMT=2 body,
// LDS tree-reduction, 8-way striped atomic stats, XCD-swizzled blockIdx.
template<int CI, int CO_PAD, int NMT, bool FUSED>
__global__ __launch_bounds__(256, 2) void conv_kernel(
    const HALF* __restrict__ h, const int* __restrict__ nbr,
    const HALF* __restrict__ Wt, HALF* __restrict__ yout,
    float* __restrict__ sums, int n,
    const float* __restrict__ psums, const float* __restrict__ pg,
    const float* __restrict__ pb, float pinvn)
{
    constexpr int K    = 27 * CI;
    constexpr int KP   = (K + 31) & ~31;
    constexpr int NCH  = KP / 32;
    constexpr int NJB  = CO_PAD / 16;
    constexpr int NW   = 4;
    constexpr int CHK  = (NCH + NW - 1) / NW;     // kc steps per wave: 14 / 7 / 4
    constexpr int NCB  = (CI >= 64) ? 2 : 1;
    static_assert(NCB == 1 || (CHK & 1) == 0, "parity must stay compile-time");
    constexpr int LOG2CI = (CI == 64) ? 6 : ((CI == 32) ? 5 : 4);
    constexpr int ROWS  = 16 * NMT;               // 32 rows per block
    constexpr int PAIRS = NMT * NJB;
    constexpr int TPW   = CHK / 2;                // taps per wave (CI=64 path): 7

    __shared__ f32x4 lred[2][PAIRS * 64];         // 16KB for CI=64/CO=64
    __shared__ float lscbi[2][64];

    const int wv   = threadIdx.x >> 6;
    const int lane = threadIdx.x & 63;
    const int l15  = lane & 15;
    const int lq   = lane >> 4;

    // bijective XCD swizzle (8 XCDs): contiguous block chunks land on one XCD
    int bid = blockIdx.x;
    {
        const int nwg = gridDim.x;
        const int q = nwg >> 3, r = nwg & 7;
        const int xcd = bid & 7, idx = bid >> 3;
        bid = (xcd < r ? xcd * (q + 1) : r * (q + 1) + (xcd - r) * q) + idx;
    }
    const int rowBase = bid * ROWS;               // same rows for all 4 waves

    // ---- in-kernel bn_prep: fold 8-way striped sums -> scale/bias in LDS
    if constexpr (FUSED) {
        const int c = threadIdx.x;
        if (c < CI) {
            float s = 0.f, q = 0.f;
#pragma unroll
            for (int k = 0; k < 8; ++k) { s += psums[k * 128 + c]; q += psums[k * 128 + CI + c]; }
            const float mu  = s * pinvn;
            const float var = q * pinvn - mu * mu;
            const float sc  = rsqrtf(var + 1e-3f) * pg[c];
            lscbi[0][c] = sc;
            lscbi[1][c] = pb[c] - mu * sc;
        }
    }

    f32x4 acc[NMT][NJB];
#pragma unroll
    for (int mt = 0; mt < NMT; ++mt)
#pragma unroll
        for (int jb = 0; jb < NJB; ++jb)
#pragma unroll
            for (int r = 0; r < 4; ++r) acc[mt][jb][r] = 0.f;

    int  nbo[NMT];
    bool rok[NMT];
#pragma unroll
    for (int mt = 0; mt < NMT; ++mt) {
        const int row = rowBase + mt * 16 + l15;
        rok[mt] = row < n;
        nbo[mt] = min(row, n - 1) * 27;
    }

    if constexpr (FUSED) __syncthreads();         // lscbi visible

    f16x8 sc8[NCB], bi8[NCB];
    if constexpr (FUSED) {
#pragma unroll
        for (int cb = 0; cb < NCB; ++cb) {
            const int c0 = cb * 32 + ((lq * 8) & (CI - 1));
#pragma unroll
            for (int j = 0; j < 8; ++j) {
                sc8[cb][j] = (HALF)lscbi[0][c0 + j];
                bi8[cb][j] = (HALF)lscbi[1][c0 + j];
            }
        }
    }

    if constexpr (CI == 64) {
        // ---- merged-tap loop: per tap, both 128B-line halves adjacent
        const int t0 = wv * TPW;                  // taps [t0, t0+7) (wave3: 21..26)

        int   ipf[2][NMT];
        f16x8 apf[2][NMT][2];
#pragma unroll
        for (int p = 0; p < 2; ++p) {
            const int t = t0 + p;
#pragma unroll
            for (int mt = 0; mt < NMT; ++mt) {
                const int v   = nbr[nbo[mt] + (t < 27 ? t : 26)];
                const int idx = (rok[mt] && t < 27) ? v : -1;
                ipf[p][mt] = idx;
                const HALF* pa = h + ((max(idx, 0) << 6) + lq * 8);
                apf[p][mt][0] = *(const f16x8*)(pa);        // ch lq*8      (parity 0)
                apf[p][mt][1] = *(const f16x8*)(pa + 32);   // ch 32+lq*8   (parity 1)
            }
        }

#pragma unroll
        for (int tt = 0; tt < TPW; ++tt) {
            const int t = t0 + tt;
            if (t >= 27) break;                   // wave-uniform (wave3 tail)
            const int cur = tt & 1;

            // take current tap's halves
            f16x8 a0[NMT], a1[NMT]; int im[NMT];
#pragma unroll
            for (int mt = 0; mt < NMT; ++mt) {
                a0[mt] = apf[cur][mt][0]; a1[mt] = apf[cur][mt][1]; im[mt] = ipf[cur][mt];
            }

            // refill with tap t+2
            if (tt + 2 < TPW && t + 2 < 27) {
#pragma unroll
                for (int mt = 0; mt < NMT; ++mt) {
                    const int v   = nbr[nbo[mt] + t + 2];
                    const int idx = rok[mt] ? v : -1;
                    ipf[cur][mt] = idx;
                    const HALF* pa = h + ((max(idx, 0) << 6) + lq * 8);
                    apf[cur][mt][0] = *(const f16x8*)(pa);
                    apf[cur][mt][1] = *(const f16x8*)(pa + 32);
                }
            }

            // B tiles for both parities of this tap (global; L1/L2-hot - R8: non-gating)
            const HALF* wb = Wt + (size_t)(2 * t) * (CO_PAD * 32) + lq * 8;
            f16x8 b0[NJB], b1[NJB];
#pragma unroll
            for (int jb = 0; jb < NJB; ++jb) {
                b0[jb] = *(const f16x8*)(wb + (size_t)(jb * 16 + l15) * 32);
                b1[jb] = *(const f16x8*)(wb + CO_PAD * 32 + (size_t)(jb * 16 + l15) * 32);
            }

            // consume parity 0 then parity 1
#pragma unroll
            for (int mt = 0; mt < NMT; ++mt) {
                f16x8 a = a0[mt];
                if constexpr (FUSED) {
                    a = a * sc8[0] + bi8[0];
#pragma unroll
                    for (int j = 0; j < 8; ++j) a[j] = (a[j] < (HALF)0.f) ? (HALF)0.f : a[j];
                }
                const int m = ~(im[mt] >> 31);
                i32x4 ai = __builtin_bit_cast(i32x4, a);
                ai.x &= m; ai.y &= m; ai.z &= m; ai.w &= m;
                a = __builtin_bit_cast(f16x8, ai);
#pragma unroll
                for (int jb = 0; jb < NJB; ++jb)
                    acc[mt][jb] = __builtin_amdgcn_mfma_f32_16x16x32_f16(a, b0[jb], acc[mt][jb], 0, 0, 0);
            }
#pragma unroll
            for (int mt = 0; mt < NMT; ++mt) {
                f16x8 a = a1[mt];
                if constexpr (FUSED) {
                    a = a * sc8[NCB - 1] + bi8[NCB - 1];
#pragma unroll
                    for (int j = 0; j < 8; ++j) a[j] = (a[j] < (HALF)0.f) ? (HALF)0.f : a[j];
                }
                const int m = ~(im[mt] >> 31);
                i32x4 ai = __builtin_bit_cast(i32x4, a);
                ai.x &= m; ai.y &= m; ai.z &= m; ai.w &= m;
                a = __builtin_bit_cast(f16x8, ai);
#pragma unroll
                for (int jb = 0; jb < NJB; ++jb)
                    acc[mt][jb] = __builtin_amdgcn_mfma_f32_16x16x32_f16(a, b1[jb], acc[mt][jb], 0, 0, 0);
            }
        }
    } else {
        // ---- R6 kc-loop (CI = 32 / 16), byte-equivalent to the 518us kernel
        const int kc0 = wv * CHK;

        int   ipf[2][NMT];
        f16x8 apf[2][NMT];
#pragma unroll
        for (int p = 0; p < 2; ++p) {
            const int kc = kc0 + p;
#pragma unroll
            for (int mt = 0; mt < NMT; ++mt) {
                const int t   = (CI == 16) ? (2 * kc + (lq >> 1)) : kc;
                const int v   = nbr[nbo[mt] + (t < 27 ? t : 26)];
                const int idx = (rok[mt] && t < 27) ? v : -1;
                ipf[p][mt] = idx;
                const int c = (CI == 32) ? (lq * 8) : ((lq & 1) * 8);
                apf[p][mt] = *(const f16x8*)(h + ((max(idx, 0) << LOG2CI) + c));
            }
        }

#pragma unroll
        for (int kc2 = 0; kc2 < CHK; ++kc2) {
            const int kc = kc0 + kc2;
            if (kc >= NCH) break;                 // wave-uniform tail guard
            const int cur = kc2 & 1;

            const HALF* wb = Wt + (size_t)kc * (CO_PAD * 32) + lq * 8;
            f16x8 b[NJB];
#pragma unroll
            for (int jb = 0; jb < NJB; ++jb)
                b[jb] = *(const f16x8*)(wb + (size_t)(jb * 16 + l15) * 32);

            f16x8 a_use[NMT];
            int   i_use[NMT];
#pragma unroll
            for (int mt = 0; mt < NMT; ++mt) { a_use[mt] = apf[cur][mt]; i_use[mt] = ipf[cur][mt]; }

            if (kc2 + 2 < CHK && kc + 2 < NCH) {
#pragma unroll
                for (int mt = 0; mt < NMT; ++mt) {
                    const int t   = (CI == 16) ? (2 * (kc + 2) + (lq >> 1)) : (kc + 2);
                    const int v   = nbr[nbo[mt] + (t < 27 ? t : 26)];
                    const int idx = (rok[mt] && t < 27) ? v : -1;
                    ipf[cur][mt] = idx;
                    const int c = (CI == 32) ? (lq * 8) : ((lq & 1) * 8);
                    apf[cur][mt] = *(const f16x8*)(h + ((max(idx, 0) << LOG2CI) + c));
                }
            }

#pragma unroll
            for (int mt = 0; mt < NMT; ++mt) {
                f16x8 a = a_use[mt];
                if constexpr (FUSED) {
                    a = a * sc8[0] + bi8[0];
#pragma unroll
                    for (int j = 0; j < 8; ++j) a[j] = (a[j] < (HALF)0.f) ? (HALF)0.f : a[j];
                }
                const int m = ~(i_use[mt] >> 31);
                i32x4 ai = __builtin_bit_cast(i32x4, a);
                ai.x &= m; ai.y &= m; ai.z &= m; ai.w &= m;
                a = __builtin_bit_cast(f16x8, ai);
#pragma unroll
                for (int jb = 0; jb < NJB; ++jb)
                    acc[mt][jb] = __builtin_amdgcn_mfma_f32_16x16x32_f16(a, b[jb], acc[mt][jb], 0, 0, 0);
            }
        }
    }

    // ---- cross-wave tree reduction of partial accumulators (3 syncs)
    if (wv & 1) {                                 // w1 -> region0, w3 -> region1
#pragma unroll
        for (int mt = 0; mt < NMT; ++mt)
#pragma unroll
            for (int jb = 0; jb < NJB; ++jb)
                lred[wv >> 1][(mt * NJB + jb) * 64 + lane] = acc[mt][jb];
    }
    __syncthreads();
    if (!(wv & 1)) {                              // w0 += region0, w2 += region1
#pragma unroll
        for (int mt = 0; mt < NMT; ++mt)
#pragma unroll
            for (int jb = 0; jb < NJB; ++jb)
                acc[mt][jb] += lred[wv >> 1][(mt * NJB + jb) * 64 + lane];
    }
    __syncthreads();                              // region0 reads done before rewrite
    if (wv == 2) {
#pragma unroll
        for (int mt = 0; mt < NMT; ++mt)
#pragma unroll
            for (int jb = 0; jb < NJB; ++jb)
                lred[0][(mt * NJB + jb) * 64 + lane] = acc[mt][jb];
    }
    __syncthreads();

    if (wv == 0) {
#pragma unroll
        for (int mt = 0; mt < NMT; ++mt)
#pragma unroll
            for (int jb = 0; jb < NJB; ++jb)
                acc[mt][jb] += lred[0][(mt * NJB + jb) * 64 + lane];

        // epilogue: store RAW pre-norm y (fp16) + per-channel sum/sumsq (8-way striped)
        float* sl = sums + (bid & 7) * 128;
#pragma unroll
        for (int jb = 0; jb < NJB; ++jb) {
            const int col = jb * 16 + l15;
            float s = 0.f, sq = 0.f;
#pragma unroll
            for (int mt = 0; mt < NMT; ++mt) {
                const int rb = rowBase + mt * 16 + lq * 4;
#pragma unroll
                for (int r = 0; r < 4; ++r) {
                    if (rb + r < n) {
                        const float v = acc[mt][jb][r];
                        yout[(size_t)(rb + r) * CO_PAD + col] = (HALF)v;
                        s += v;
                        sq += v * v;
                    }
                }
            }
            s  += __shfl_xor(s, 16);  s  += __shfl_xor(s, 32);
            sq += __shfl_xor(sq, 16); sq += __shfl_xor(sq, 32);
            if (lane < 16) {
                atomicAdd(&sl[col], s);
                atomicAdd(&sl[CO_PAD + col], sq);
            }
        }
    }
}

// ---- final: normalize (no relu), co=3 out of CO_PAD=16, fp32 output; striped sums
__global__ void bn_out_kernel(const HALF* __restrict__ y, const float* __restrict__ sums,
                              const float* __restrict__ g, const float* __restrict__ b,
                              int n, float invn, float* __restrict__ out)
{
    int i = blockIdx.x * 256 + threadIdx.x;
    if (i >= n * 3) return;
    int row = i / 3;
    int c = i - row * 3;
    float ssum = 0.f, qsum = 0.f;
#pragma unroll
    for (int k2 = 0; k2 < 8; ++k2) {
        ssum += sums[k2 * 128 + c];
        qsum += sums[k2 * 128 + 16 + c];
    }
    float mu  = ssum * invn;
    float var = qsum * invn - mu * mu;
    float sc  = rsqrtf(var + 1e-3f) * g[c];
    out[i] = ((float)y[(size_t)row * 16 + c] - mu) * sc + b[c];
}

extern "C" void kernel_launch(void* const* d_in, const int* in_sizes, int n_in,
                              void* d_out, int out_size, void* d_ws, size_t ws_size,
                              hipStream_t stream)
{
    const int* nbr4  = (const int*)d_in[0];
    const int* inv43 = (const int*)d_in[1];
    const int* nbr3  = (const int*)d_in[2];
    const int* inv32 = (const int*)d_in[3];
    const int* nbr2  = (const int*)d_in[4];
    const int* inv21 = (const int*)d_in[5];
    const int* nbr1  = (const int*)d_in[6];
    const float* x   = (const float*)d_in[7];

    const int n4 = in_sizes[0] / 27;
    const int n3 = in_sizes[1] / 27;
    const int n2 = in_sizes[3] / 27;
    const int n1 = in_sizes[5] / 27;

    // specs: m4,i4,m3,i3,m2,i2,m1,c5
    const int CIs[8]  = {64, 64, 64, 64, 32, 32, 16, 16};
    const int COPs[8] = {64, 64, 64, 32, 32, 16, 16, 16};
    int KPs[8], wtoff[8];
    int wtot = 0;
    for (int s = 0; s < 8; ++s) {
        KPs[s] = ((27 * CIs[s] + 31) / 32) * 32;
        wtoff[s] = wtot;
        wtot += COPs[s] * KPs[s];
    }

    char* ws = (char*)d_ws;
    HALF* wt = (HALF*)ws;
    size_t off = ((size_t)wtot * sizeof(HALF) + 255) & ~(size_t)255;
    float* sums = (float*)(ws + off);
    off += 8 * 1024 * sizeof(float);              // 8 layers x 8 stripes x 128 floats
    off = (off + 255) & ~(size_t)255;
    HALF* xh = (HALF*)(ws + off);
    off += ((size_t)n4 * 64 * sizeof(HALF) + 255) & ~(size_t)255;
    size_t bufElems = 0;
    {
        size_t cand[4] = {(size_t)n4 * 64, (size_t)n3 * 64, (size_t)n2 * 32, (size_t)n1 * 16};
        for (int i = 0; i < 4; ++i) if (cand[i] > bufElems) bufElems = cand[i];
    }
    HALF* Y0 = (HALF*)(ws + off);
    off += (bufElems * sizeof(HALF) + 255) & ~(size_t)255;
    HALF* Y1 = (HALF*)(ws + off);

    hipMemsetAsync(sums, 0, 8 * 1024 * sizeof(float), stream);

    WArgs wa;
    for (int s = 0; s < 8; ++s) { wa.W[s] = (const float*)d_in[8 + 3 * s]; wa.dst[s] = wt + wtoff[s]; }
    {
        int maxTotal = 64 * KPs[0];
        dim3 grid((maxTotal + 255) / 256, 8);
        convert_all_w_kernel<<<grid, 256, 0, stream>>>(wa);
    }
    convert_x_kernel<<<(n4 * 64 + 255) / 256, 256, 0, stream>>>(x, xh, n4 * 64);

#define G(s) ((const float*)d_in[9 + 3 * (s)])
#define B(s) ((const float*)d_in[10 + 3 * (s)])
#define SUMS(s) (sums + (s) * 1024)
#define GRID(nn) (((nn) + 31) / 32)

    // m4: xh(n4,64) -> Y0 (raw)
    conv_kernel<64, 64, 2, false><<<GRID(n4), 256, 0, stream>>>(
        xh, nbr4, wt + wtoff[0], Y0, SUMS(0), n4, nullptr, nullptr, nullptr, 0.f);
    // i4: norm(m4) fused; Y0(n4) -> Y1(n3)
    conv_kernel<64, 64, 2, true><<<GRID(n3), 256, 0, stream>>>(
        Y0, inv43, wt + wtoff[1], Y1, SUMS(1), n3, SUMS(0), G(0), B(0), 1.f / n4);
    // m3: norm(i4) fused; Y1 -> Y0
    conv_kernel<64, 64, 2, true><<<GRID(n3), 256, 0, stream>>>(
        Y1, nbr3, wt + wtoff[2], Y0, SUMS(2), n3, SUMS(1), G(1), B(1), 1.f / n3);
    // i3: norm(m3) fused; Y0(n3) -> Y1(n2), co 32
    conv_kernel<64, 32, 2, true><<<GRID(n2), 256, 0, stream>>>(
        Y0, inv32, wt + wtoff[3], Y1, SUMS(3), n2, SUMS(2), G(2), B(2), 1.f / n3);
    // m2: norm(i3) fused; Y1 -> Y0
    conv_kernel<32, 32, 2, true><<<GRID(n2), 256, 0, stream>>>(
        Y1, nbr2, wt + wtoff[4], Y0, SUMS(4), n2, SUMS(3), G(3), B(3), 1.f / n2);
    // i2: norm(m2) fused; Y0(n2) -> Y1(n1), co 16
    conv_kernel<32, 16, 2, true><<<GRID(n1), 256, 0, stream>>>(
        Y0, inv21, wt + wtoff[5], Y1, SUMS(5), n1, SUMS(4), G(4), B(4), 1.f / n2);
    // m1: norm(i2) fused; Y1 -> Y0
    conv_kernel<16, 16, 2, true><<<GRID(n1), 256, 0, stream>>>(
        Y1, nbr1, wt + wtoff[6], Y0, SUMS(6), n1, SUMS(5), G(5), B(5), 1.f / n1);
    // c5: norm(m1) fused; Y0 -> Y1 (raw), then fp32 out
    conv_kernel<16, 16, 2, true><<<GRID(n1), 256, 0, stream>>>(
        Y0, nbr1, wt + wtoff[7], Y1, SUMS(7), n1, SUMS(6), G(6), B(6), 1.f / n1);
    bn_out_kernel<<<(n1 * 3 + 255) / 256, 256, 0, stream>>>(
        Y1, SUMS(7), G(7), B(7), n1, 1.f / n1, (float*)d_out);

#undef G
#undef B
#undef SUMS
#undef GRID
}

// Round 12
// 476.493 us; speedup vs baseline: 1.2439x; 1.0132x over previous
//
#include <hip/hip_runtime.h>

typedef _Float16 HALF;
typedef _Float16 f16x8 __attribute__((ext_vector_type(8)));
typedef float f32x4 __attribute__((ext_vector_type(4)));
typedef int i32x4 __attribute__((ext_vector_type(4)));

// ---- fused weight conversion: fp32 (27*CI, CO) -> fp16 tiled [KP/32][CO_PAD][32], zero padded
struct WArgs { const float* W[8]; HALF* dst[8]; };

__global__ void convert_all_w_kernel(WArgs a)
{
    const int CIs[8]  = {64, 64, 64, 64, 32, 32, 16, 16};
    const int COs[8]  = {64, 64, 64, 32, 32, 16, 16, 3};
    const int COPs[8] = {64, 64, 64, 32, 32, 16, 16, 16};
    const int L = blockIdx.y;
    const int CI = CIs[L], CO = COs[L], COP = COPs[L];
    const int K = 27 * CI, KP = (K + 31) & ~31;
    const int total = COP * KP;
    for (int i = blockIdx.x * 256 + threadIdx.x; i < total; i += gridDim.x * 256) {
        int jp = i / KP;          // out channel (padded)
        int kp = i - jp * KP;     // k (padded)
        float v = (jp < CO && kp < K) ? a.W[L][(size_t)kp * CO + jp] : 0.f;
        a.dst[L][((size_t)(kp >> 5) * COP + jp) * 32 + (kp & 31)] = (HALF)v;
    }
}

__global__ void convert_x_kernel(const float* __restrict__ x, HALF* __restrict__ xh, int total)
{
    int i = blockIdx.x * 256 + threadIdx.x;
    if (i < total) xh[i] = (HALF)x[i];
}

// ---- conv: R10 structure (k-split, merged-tap, bn-fold) + per-block ACTIVE-TAP
// compaction. Voxel grids are sparse (occupancy 0.1%..37% by level): most of the
// 27 taps have NO valid neighbor in a 32-row block (nbr1: ~2 active taps, nbr2:
// ~7, inv: ~8-14). Skipping all-invalid taps is bitwise exact (masked lanes
// contribute exactly 0.0 to the f32 MFMA accumulate). Prologue: stage nbr slice
// to LDS, 27-thread validity scan, thread-0 compaction into tls[] (sentinel 27
// = "no tap": idx=-1, B addr clamped, contribution masked). Waves round-robin
// the compact list (i = wv; i < NT; i += 4) -> k-split reduction unchanged.
// CI=64 keeps the proven static path when NT==27 (m4 always; occasionally m3).
template<int CI, int CO_PAD, bool FUSED>
__global__ __launch_bounds__(256, 2) void conv_kernel(
    const HALF* __restrict__ h, const int* __restrict__ nbr,
    const HALF* __restrict__ Wt, HALF* __restrict__ yout,
    float* __restrict__ sums, int n,
    const float* __restrict__ psums, const float* __restrict__ pg,
    const float* __restrict__ pb, float pinvn)
{
    constexpr int NMT   = 2;
    constexpr int NJB   = CO_PAD / 16;
    constexpr int NCB   = (CI >= 64) ? 2 : 1;
    constexpr int LOG2CI = (CI == 64) ? 6 : ((CI == 32) ? 5 : 4);
    constexpr int ROWS  = 32;
    constexpr int PAIRS = NMT * NJB;

    __shared__ f32x4 lred[2][PAIRS * 64];         // 16KB for CI=64/CO=64
    __shared__ float lscbi[2][64];
    __shared__ int   lidx[ROWS * 27];
    __shared__ int   tflag[27];
    __shared__ int   tls[32];                     // compact tap list, sentinel-padded
    __shared__ int   ntapS;

    const int wv   = threadIdx.x >> 6;
    const int lane = threadIdx.x & 63;
    const int l15  = lane & 15;
    const int lq   = lane >> 4;

    // bijective XCD swizzle (8 XCDs): contiguous row ranges share an XCD L2
    int bid = blockIdx.x;
    {
        const int nwg = gridDim.x;
        const int q = nwg >> 3, r = nwg & 7;
        const int xcd = bid & 7, idx = bid >> 3;
        bid = (xcd < r ? xcd * (q + 1) : r * (q + 1) + (xcd - r) * q) + idx;
    }
    const int rowBase = bid * ROWS;               // same rows for all 4 waves

    // ---- stage nbr slice to LDS (coalesced; OOB rows -> -1)
    for (int i = threadIdx.x; i < ROWS * 27; i += 256) {
        const int r   = i / 27;
        const int row = rowBase + r;
        lidx[i] = (row < n) ? nbr[(size_t)row * 27 + (i - r * 27)] : -1;
    }
    // ---- in-kernel bn_prep: fold 8-way striped sums -> scale/bias in LDS
    if constexpr (FUSED) {
        const int c = threadIdx.x;
        if (c < CI) {
            float s = 0.f, q = 0.f;
#pragma unroll
            for (int k = 0; k < 8; ++k) { s += psums[k * 128 + c]; q += psums[k * 128 + CI + c]; }
            const float mu  = s * pinvn;
            const float var = q * pinvn - mu * mu;
            const float sc  = rsqrtf(var + 1e-3f) * pg[c];
            lscbi[0][c] = sc;
            lscbi[1][c] = pb[c] - mu * sc;
        }
    }
    __syncthreads();

    // ---- per-tap any-valid scan (27 threads, all in wave 0)
    if (threadIdx.x < 27) {
        int any = 0;
        for (int r = 0; r < ROWS; ++r) any |= ~(lidx[r * 27 + threadIdx.x] >> 31);
        tflag[threadIdx.x] = any & 1;
    }
    __syncthreads();
    if (threadIdx.x == 0) {
        int c = 0;
#pragma unroll
        for (int t = 0; t < 27; ++t) if (tflag[t]) tls[c++] = t;
        ntapS = c;
        for (int t = c; t < 32; ++t) tls[t] = 27;  // sentinel pad
    }
    __syncthreads();
    const int NT = ntapS;

    f16x8 sc8[NCB], bi8[NCB];
    if constexpr (FUSED) {
#pragma unroll
        for (int cb = 0; cb < NCB; ++cb) {
            const int c0 = cb * 32 + ((lq * 8) & (CI - 1));
#pragma unroll
            for (int j = 0; j < 8; ++j) {
                sc8[cb][j] = (HALF)lscbi[0][c0 + j];
                bi8[cb][j] = (HALF)lscbi[1][c0 + j];
            }
        }
    }

    f32x4 acc[NMT][NJB];
#pragma unroll
    for (int mt = 0; mt < NMT; ++mt)
#pragma unroll
        for (int jb = 0; jb < NJB; ++jb)
#pragma unroll
            for (int r = 0; r < 4; ++r) acc[mt][jb][r] = 0.f;

    int lb[NMT];
#pragma unroll
    for (int mt = 0; mt < NMT; ++mt) lb[mt] = (mt * 16 + l15) * 27;

    // consume helper (bn+relu, mask, MFMA pair) shared by all CI=64 paths
    #define CONSUME64(aV_, imV_, bV_, CBIDX_) do { \
        f16x8 a_ = (aV_); \
        if constexpr (FUSED) { \
            a_ = a_ * sc8[CBIDX_] + bi8[CBIDX_]; \
            _Pragma("unroll") \
            for (int j_ = 0; j_ < 8; ++j_) a_[j_] = (a_[j_] < (HALF)0.f) ? (HALF)0.f : a_[j_]; \
        } \
        const int m_ = ~((imV_) >> 31); \
        i32x4 ai_ = __builtin_bit_cast(i32x4, a_); \
        ai_.x &= m_; ai_.y &= m_; ai_.z &= m_; ai_.w &= m_; \
        a_ = __builtin_bit_cast(f16x8, ai_); \
        _Pragma("unroll") \
        for (int jb_ = 0; jb_ < NJB; ++jb_) \
            acc[mt][jb_] = __builtin_amdgcn_mfma_f32_16x16x32_f16(a_, (bV_)[jb_], acc[mt][jb_], 0, 0, 0); \
    } while (0)

    if constexpr (CI == 64) {
        if (NT == 27) {
            // ---- static merged-tap path (R10, proven): taps wv*7 .. +7
            constexpr int TPW = 7;
            const int t0 = wv * TPW;

            int   ipf[2][NMT];
            f16x8 apf[2][NMT][2];
#pragma unroll
            for (int p = 0; p < 2; ++p) {
                const int t = t0 + p;
#pragma unroll
                for (int mt = 0; mt < NMT; ++mt) {
                    const int idx = (t < 27) ? lidx[lb[mt] + (t < 27 ? t : 26)] : -1;
                    ipf[p][mt] = idx;
                    const HALF* pa = h + ((max(idx, 0) << 6) + lq * 8);
                    apf[p][mt][0] = *(const f16x8*)(pa);
                    apf[p][mt][1] = *(const f16x8*)(pa + 32);
                }
            }

#pragma unroll
            for (int tt = 0; tt < TPW; ++tt) {
                const int t = t0 + tt;
                if (t >= 27) break;               // wave-uniform (wave3 tail)
                const int cur = tt & 1;

                f16x8 a0[NMT], a1[NMT]; int im[NMT];
#pragma unroll
                for (int mt = 0; mt < NMT; ++mt) {
                    a0[mt] = apf[cur][mt][0]; a1[mt] = apf[cur][mt][1]; im[mt] = ipf[cur][mt];
                }

                if (tt + 2 < TPW && t + 2 < 27) {
#pragma unroll
                    for (int mt = 0; mt < NMT; ++mt) {
                        const int idx = lidx[lb[mt] + t + 2];
                        ipf[cur][mt] = idx;
                        const HALF* pa = h + ((max(idx, 0) << 6) + lq * 8);
                        apf[cur][mt][0] = *(const f16x8*)(pa);
                        apf[cur][mt][1] = *(const f16x8*)(pa + 32);
                    }
                }

                const HALF* wb = Wt + (size_t)(2 * t) * (CO_PAD * 32) + lq * 8;
                f16x8 b0[NJB], b1[NJB];
#pragma unroll
                for (int jb = 0; jb < NJB; ++jb) {
                    b0[jb] = *(const f16x8*)(wb + (size_t)(jb * 16 + l15) * 32);
                    b1[jb] = *(const f16x8*)(wb + CO_PAD * 32 + (size_t)(jb * 16 + l15) * 32);
                }

#pragma unroll
                for (int mt = 0; mt < NMT; ++mt) CONSUME64(a0[mt], im[mt], b0, 0);
#pragma unroll
                for (int mt = 0; mt < NMT; ++mt) CONSUME64(a1[mt], im[mt], b1, NCB - 1);
            }
        } else {
            // ---- dynamic compact-tap path: waves round-robin tls[0..NT)
            int ti = wv;
            int   tcur, icur[NMT];
            f16x8 a0c[NMT], a1c[NMT];
            {
                tcur = tls[ti];                   // sentinel-safe (padded)
#pragma unroll
                for (int mt = 0; mt < NMT; ++mt) {
                    const int idx = (tcur < 27) ? lidx[lb[mt] + min(tcur, 26)] : -1;
                    icur[mt] = idx;
                    const HALF* pa = h + ((max(idx, 0) << 6) + lq * 8);
                    a0c[mt] = *(const f16x8*)(pa);
                    a1c[mt] = *(const f16x8*)(pa + 32);
                }
            }
            for (; ti < NT; ti += 4) {
                // prefetch stage ti+4 (sentinel-safe clamp)
                int   tnx = tls[min(ti + 4, 31)];
                int   inx[NMT];
                f16x8 a0n[NMT], a1n[NMT];
#pragma unroll
                for (int mt = 0; mt < NMT; ++mt) {
                    const int idx = (tnx < 27) ? lidx[lb[mt] + min(tnx, 26)] : -1;
                    inx[mt] = idx;
                    const HALF* pa = h + ((max(idx, 0) << 6) + lq * 8);
                    a0n[mt] = *(const f16x8*)(pa);
                    a1n[mt] = *(const f16x8*)(pa + 32);
                }

                const HALF* wb = Wt + (size_t)(2 * tcur) * (CO_PAD * 32) + lq * 8;
                f16x8 b0[NJB], b1[NJB];
#pragma unroll
                for (int jb = 0; jb < NJB; ++jb) {
                    b0[jb] = *(const f16x8*)(wb + (size_t)(jb * 16 + l15) * 32);
                    b1[jb] = *(const f16x8*)(wb + CO_PAD * 32 + (size_t)(jb * 16 + l15) * 32);
                }

#pragma unroll
                for (int mt = 0; mt < NMT; ++mt) CONSUME64(a0c[mt], icur[mt], b0, 0);
#pragma unroll
                for (int mt = 0; mt < NMT; ++mt) CONSUME64(a1c[mt], icur[mt], b1, NCB - 1);

                // rotate
                tcur = tnx;
#pragma unroll
                for (int mt = 0; mt < NMT; ++mt) {
                    icur[mt] = inx[mt]; a0c[mt] = a0n[mt]; a1c[mt] = a1n[mt];
                }
            }
        }
    } else if constexpr (CI == 32) {
        // ---- dynamic compact-tap path, one 32ch slice per tap
        int ti = wv;
        int   tcur, icur[NMT];
        f16x8 ac[NMT];
        {
            tcur = tls[ti];
#pragma unroll
            for (int mt = 0; mt < NMT; ++mt) {
                const int idx = (tcur < 27) ? lidx[lb[mt] + min(tcur, 26)] : -1;
                icur[mt] = idx;
                ac[mt] = *(const f16x8*)(h + ((max(idx, 0) << 5) + lq * 8));
            }
        }
        for (; ti < NT; ti += 4) {
            int   tnx = tls[min(ti + 4, 31)];
            int   inx[NMT];
            f16x8 an[NMT];
#pragma unroll
            for (int mt = 0; mt < NMT; ++mt) {
                const int idx = (tnx < 27) ? lidx[lb[mt] + min(tnx, 26)] : -1;
                inx[mt] = idx;
                an[mt] = *(const f16x8*)(h + ((max(idx, 0) << 5) + lq * 8));
            }

            const HALF* wb = Wt + (size_t)tcur * (CO_PAD * 32) + lq * 8;
            f16x8 b[NJB];
#pragma unroll
            for (int jb = 0; jb < NJB; ++jb)
                b[jb] = *(const f16x8*)(wb + (size_t)(jb * 16 + l15) * 32);

#pragma unroll
            for (int mt = 0; mt < NMT; ++mt) CONSUME64(ac[mt], icur[mt], b, 0);

            tcur = tnx;
#pragma unroll
            for (int mt = 0; mt < NMT; ++mt) { icur[mt] = inx[mt]; ac[mt] = an[mt]; }
        }
    } else {
        // ---- CI == 16: two list entries per MFMA step (lq>>1 selects);
        // sentinel tap 27 -> idx=-1 (masked to 0), B address clamped.
        const int NS = (NT + 1) >> 1;
        int ti = wv;
        int   tcur, icur[NMT];
        f16x8 ac[NMT];
        {
            tcur = tls[min(2 * ti + (lq >> 1), 31)];
#pragma unroll
            for (int mt = 0; mt < NMT; ++mt) {
                const int idx = (tcur < 27) ? lidx[lb[mt] + min(tcur, 26)] : -1;
                icur[mt] = idx;
                ac[mt] = *(const f16x8*)(h + ((max(idx, 0) << 4) + (lq & 1) * 8));
            }
        }
        for (; ti < NS; ti += 4) {
            int   tnx = tls[min(2 * (ti + 4) + (lq >> 1), 31)];
            int   inx[NMT];
            f16x8 an[NMT];
#pragma unroll
            for (int mt = 0; mt < NMT; ++mt) {
                const int idx = (tnx < 27) ? lidx[lb[mt] + min(tnx, 26)] : -1;
                inx[mt] = idx;
                an[mt] = *(const f16x8*)(h + ((max(idx, 0) << 4) + (lq & 1) * 8));
            }

            // per-lane B address from this lane's tap (clamped for sentinel)
            const int tb = min(tcur, 26);
            f16x8 b[NJB];
#pragma unroll
            for (int jb = 0; jb < NJB; ++jb)
                b[jb] = *(const f16x8*)(Wt + (size_t)(tb >> 1) * (CO_PAD * 32)
                                        + (size_t)(jb * 16 + l15) * 32 + (tb & 1) * 16 + (lq & 1) * 8);

#pragma unroll
            for (int mt = 0; mt < NMT; ++mt) CONSUME64(ac[mt], icur[mt], b, 0);

            tcur = tnx;
#pragma unroll
            for (int mt = 0; mt < NMT; ++mt) { icur[mt] = inx[mt]; ac[mt] = an[mt]; }
        }
    }
    #undef CONSUME64

    // ---- cross-wave tree reduction of partial accumulators (3 syncs)
    if (wv & 1) {
#pragma unroll
        for (int mt = 0; mt < NMT; ++mt)
#pragma unroll
            for (int jb = 0; jb < NJB; ++jb)
                lred[wv >> 1][(mt * NJB + jb) * 64 + lane] = acc[mt][jb];
    }
    __syncthreads();
    if (!(wv & 1)) {
#pragma unroll
        for (int mt = 0; mt < NMT; ++mt)
#pragma unroll
            for (int jb = 0; jb < NJB; ++jb)
                acc[mt][jb] += lred[wv >> 1][(mt * NJB + jb) * 64 + lane];
    }
    __syncthreads();
    if (wv == 2) {
#pragma unroll
        for (int mt = 0; mt < NMT; ++mt)
#pragma unroll
            for (int jb = 0; jb < NJB; ++jb)
                lred[0][(mt * NJB + jb) * 64 + lane] = acc[mt][jb];
    }
    __syncthreads();

    if (wv == 0) {
#pragma unroll
        for (int mt = 0; mt < NMT; ++mt)
#pragma unroll
            for (int jb = 0; jb < NJB; ++jb)
                acc[mt][jb] += lred[0][(mt * NJB + jb) * 64 + lane];

        // epilogue: store RAW pre-norm y (fp16) + per-channel sum/sumsq (8-way striped)
        float* sl = sums + (bid & 7) * 128;
#pragma unroll
        for (int jb = 0; jb < NJB; ++jb) {
            const int col = jb * 16 + l15;
            float s = 0.f, sq = 0.f;
#pragma unroll
            for (int mt = 0; mt < NMT; ++mt) {
                const int rb = rowBase + mt * 16 + lq * 4;
#pragma unroll
                for (int r = 0; r < 4; ++r) {
                    if (rb + r < n) {
                        const float v = acc[mt][jb][r];
                        yout[(size_t)(rb + r) * CO_PAD + col] = (HALF)v;
                        s += v;
                        sq += v * v;
                    }
                }
            }
            s  += __shfl_xor(s, 16);  s  += __shfl_xor(s, 32);
            sq += __shfl_xor(sq, 16); sq += __shfl_xor(sq, 32);
            if (lane < 16) {
                atomicAdd(&sl[col], s);
                atomicAdd(&sl[CO_PAD + col], sq);
            }
        }
    }
}

// ---- final: normalize (no relu), co=3 out of CO_PAD=16, fp32 output; striped sums
__global__ void bn_out_kernel(const HALF* __restrict__ y, const float* __restrict__ sums,
                              const float* __restrict__ g, const float* __restrict__ b,
                              int n, float invn, float* __restrict__ out)
{
    int i = blockIdx.x * 256 + threadIdx.x;
    if (i >= n * 3) return;
    int row = i / 3;
    int c = i - row * 3;
    float ssum = 0.f, qsum = 0.f;
#pragma unroll
    for (int k2 = 0; k2 < 8; ++k2) {
        ssum += sums[k2 * 128 + c];
        qsum += sums[k2 * 128 + 16 + c];
    }
    float mu  = ssum * invn;
    float var = qsum * invn - mu * mu;
    float sc  = rsqrtf(var + 1e-3f) * g[c];
    out[i] = ((float)y[(size_t)row * 16 + c] - mu) * sc + b[c];
}

extern "C" void kernel_launch(void* const* d_in, const int* in_sizes, int n_in,
                              void* d_out, int out_size, void* d_ws, size_t ws_size,
                              hipStream_t stream)
{
    const int* nbr4  = (const int*)d_in[0];
    const int* inv43 = (const int*)d_in[1];
    const int* nbr3  = (const int*)d_in[2];
    const int* inv32 = (const int*)d_in[3];
    const int* nbr2  = (const int*)d_in[4];
    const int* inv21 = (const int*)d_in[5];
    const int* nbr1  = (const int*)d_in[6];
    const float* x   = (const float*)d_in[7];

    const int n4 = in_sizes[0] / 27;
    const int n3 = in_sizes[1] / 27;
    const int n2 = in_sizes[3] / 27;
    const int n1 = in_sizes[5] / 27;

    // specs: m4,i4,m3,i3,m2,i2,m1,c5
    const int CIs[8]  = {64, 64, 64, 64, 32, 32, 16, 16};
    const int COPs[8] = {64, 64, 64, 32, 32, 16, 16, 16};
    int KPs[8], wtoff[8];
    int wtot = 0;
    for (int s = 0; s < 8; ++s) {
        KPs[s] = ((27 * CIs[s] + 31) / 32) * 32;
        wtoff[s] = wtot;
        wtot += COPs[s] * KPs[s];
    }

    char* ws = (char*)d_ws;
    HALF* wt = (HALF*)ws;
    size_t off = ((size_t)wtot * sizeof(HALF) + 255) & ~(size_t)255;
    float* sums = (float*)(ws + off);
    off += 8 * 1024 * sizeof(float);              // 8 layers x 8 stripes x 128 floats
    off = (off + 255) & ~(size_t)255;
    HALF* xh = (HALF*)(ws + off);
    off += ((size_t)n4 * 64 * sizeof(HALF) + 255) & ~(size_t)255;
    size_t bufElems = 0;
    {
        size_t cand[4] = {(size_t)n4 * 64, (size_t)n3 * 64, (size_t)n2 * 32, (size_t)n1 * 16};
        for (int i = 0; i < 4; ++i) if (cand[i] > bufElems) bufElems = cand[i];
    }
    HALF* Y0 = (HALF*)(ws + off);
    off += (bufElems * sizeof(HALF) + 255) & ~(size_t)255;
    HALF* Y1 = (HALF*)(ws + off);

    hipMemsetAsync(sums, 0, 8 * 1024 * sizeof(float), stream);

    WArgs wa;
    for (int s = 0; s < 8; ++s) { wa.W[s] = (const float*)d_in[8 + 3 * s]; wa.dst[s] = wt + wtoff[s]; }
    {
        int maxTotal = 64 * KPs[0];
        dim3 grid((maxTotal + 255) / 256, 8);
        convert_all_w_kernel<<<grid, 256, 0, stream>>>(wa);
    }
    convert_x_kernel<<<(n4 * 64 + 255) / 256, 256, 0, stream>>>(x, xh, n4 * 64);

#define G(s) ((const float*)d_in[9 + 3 * (s)])
#define B(s) ((const float*)d_in[10 + 3 * (s)])
#define SUMS(s) (sums + (s) * 1024)
#define GRID(nn) (((nn) + 31) / 32)

    // m4: xh(n4,64) -> Y0 (raw)
    conv_kernel<64, 64, false><<<GRID(n4), 256, 0, stream>>>(
        xh, nbr4, wt + wtoff[0], Y0, SUMS(0), n4, nullptr, nullptr, nullptr, 0.f);
    // i4: norm(m4) fused; Y0(n4) -> Y1(n3)
    conv_kernel<64, 64, true><<<GRID(n3), 256, 0, stream>>>(
        Y0, inv43, wt + wtoff[1], Y1, SUMS(1), n3, SUMS(0), G(0), B(0), 1.f / n4);
    // m3: norm(i4) fused; Y1 -> Y0
    conv_kernel<64, 64, true><<<GRID(n3), 256, 0, stream>>>(
        Y1, nbr3, wt + wtoff[2], Y0, SUMS(2), n3, SUMS(1), G(1), B(1), 1.f / n3);
    // i3: norm(m3) fused; Y0(n3) -> Y1(n2), co 32
    conv_kernel<64, 32, true><<<GRID(n2), 256, 0, stream>>>(
        Y0, inv32, wt + wtoff[3], Y1, SUMS(3), n2, SUMS(2), G(2), B(2), 1.f / n3);
    // m2: norm(i3) fused; Y1 -> Y0
    conv_kernel<32, 32, true><<<GRID(n2), 256, 0, stream>>>(
        Y1, nbr2, wt + wtoff[4], Y0, SUMS(4), n2, SUMS(3), G(3), B(3), 1.f / n2);
    // i2: norm(m2) fused; Y0(n2) -> Y1(n1), co 16
    conv_kernel<32, 16, true><<<GRID(n1), 256, 0, stream>>>(
        Y0, inv21, wt + wtoff[5], Y1, SUMS(5), n1, SUMS(4), G(4), B(4), 1.f / n2);
    // m1: norm(i2) fused; Y1 -> Y0
    conv_kernel<16, 16, true><<<GRID(n1), 256, 0, stream>>>(
        Y1, nbr1, wt + wtoff[6], Y0, SUMS(6), n1, SUMS(5), G(5), B(5), 1.f / n1);
    // c5: norm(m1) fused; Y0 -> Y1 (raw), then fp32 out
    conv_kernel<16, 16, true><<<GRID(n1), 256, 0, stream>>>(
        Y0, nbr1, wt + wtoff[7], Y1, SUMS(7), n1, SUMS(6), G(6), B(6), 1.f / n1);
    bn_out_kernel<<<(n1 * 3 + 255) / 256, 256, 0, stream>>>(
        Y1, SUMS(7), G(7), B(7), n1, 1.f / n1, (float*)d_out);

#undef G
#undef B
#undef SUMS
#undef GRID
}

// Round 13
// 462.564 us; speedup vs baseline: 1.2814x; 1.0301x over previous
//
#include <hip/hip_runtime.h>

typedef _Float16 HALF;
typedef _Float16 f16x8 __attribute__((ext_vector_type(8)));
typedef float f32x4 __attribute__((ext_vector_type(4)));
typedef int i32x4 __attribute__((ext_vector_type(4)));

// ---- fused weight conversion: fp32 (27*CI, CO) -> fp16 tiled [KP/32][CO_PAD][32], zero padded
struct WArgs { const float* W[8]; HALF* dst[8]; };

__global__ void convert_all_w_kernel(WArgs a)
{
    const int CIs[8]  = {64, 64, 64, 64, 32, 32, 16, 16};
    const int COs[8]  = {64, 64, 64, 32, 32, 16, 16, 3};
    const int COPs[8] = {64, 64, 64, 32, 32, 16, 16, 16};
    const int L = blockIdx.y;
    const int CI = CIs[L], CO = COs[L], COP = COPs[L];
    const int K = 27 * CI, KP = (K + 31) & ~31;
    const int total = COP * KP;
    for (int i = blockIdx.x * 256 + threadIdx.x; i < total; i += gridDim.x * 256) {
        int jp = i / KP;          // out channel (padded)
        int kp = i - jp * KP;     // k (padded)
        float v = (jp < CO && kp < K) ? a.W[L][(size_t)kp * CO + jp] : 0.f;
        a.dst[L][((size_t)(kp >> 5) * COP + jp) * 32 + (kp & 31)] = (HALF)v;
    }
}

__global__ void convert_x_kernel(const float* __restrict__ x, HALF* __restrict__ xh, int total)
{
    int i = blockIdx.x * 256 + threadIdx.x;
    if (i < total) xh[i] = (HALF)x[i];
}

// ================= conv_static: exact R10 merged-tap kernel (CI=64 only) =================
// k-split across 4 waves by tap (7/wave); both 64B halves of each row's 128B line
// loaded adjacently; 2-deep rolling prefetch; in-kernel bn_prep; LDS tree-reduce.
// Used for m4/i4/m3 where the per-block tap union is ~27 (R12 evidence: FETCH
// unchanged, dynamic path lost 9us/layer there). SEPARATE kernel so the dynamic
// path's regalloc can't squeeze this one (R12: VGPR 76->68 cost 12%).
template<int CO_PAD, bool FUSED>
__global__ __launch_bounds__(256, 2) void conv_static(
    const HALF* __restrict__ h, const int* __restrict__ nbr,
    const HALF* __restrict__ Wt, HALF* __restrict__ yout,
    float* __restrict__ sums, int n,
    const float* __restrict__ psums, const float* __restrict__ pg,
    const float* __restrict__ pb, float pinvn)
{
    constexpr int CI   = 64;
    constexpr int NMT  = 2;
    constexpr int NJB  = CO_PAD / 16;
    constexpr int NCB  = 2;
    constexpr int ROWS = 32;
    constexpr int PAIRS = NMT * NJB;
    constexpr int TPW  = 7;

    __shared__ f32x4 lred[2][PAIRS * 64];
    __shared__ float lscbi[2][64];

    const int wv   = threadIdx.x >> 6;
    const int lane = threadIdx.x & 63;
    const int l15  = lane & 15;
    const int lq   = lane >> 4;

    int bid = blockIdx.x;
    {
        const int nwg = gridDim.x;
        const int q = nwg >> 3, r = nwg & 7;
        const int xcd = bid & 7, idx = bid >> 3;
        bid = (xcd < r ? xcd * (q + 1) : r * (q + 1) + (xcd - r) * q) + idx;
    }
    const int rowBase = bid * ROWS;

    if constexpr (FUSED) {
        const int c = threadIdx.x;
        if (c < CI) {
            float s = 0.f, q = 0.f;
#pragma unroll
            for (int k = 0; k < 8; ++k) { s += psums[k * 128 + c]; q += psums[k * 128 + CI + c]; }
            const float mu  = s * pinvn;
            const float var = q * pinvn - mu * mu;
            const float sc  = rsqrtf(var + 1e-3f) * pg[c];
            lscbi[0][c] = sc;
            lscbi[1][c] = pb[c] - mu * sc;
        }
    }

    f32x4 acc[NMT][NJB];
#pragma unroll
    for (int mt = 0; mt < NMT; ++mt)
#pragma unroll
        for (int jb = 0; jb < NJB; ++jb)
#pragma unroll
            for (int r = 0; r < 4; ++r) acc[mt][jb][r] = 0.f;

    int  nbo[NMT];
    bool rok[NMT];
#pragma unroll
    for (int mt = 0; mt < NMT; ++mt) {
        const int row = rowBase + mt * 16 + l15;
        rok[mt] = row < n;
        nbo[mt] = min(row, n - 1) * 27;
    }

    if constexpr (FUSED) __syncthreads();

    f16x8 sc8[NCB], bi8[NCB];
    if constexpr (FUSED) {
#pragma unroll
        for (int cb = 0; cb < NCB; ++cb) {
            const int c0 = cb * 32 + ((lq * 8) & (CI - 1));
#pragma unroll
            for (int j = 0; j < 8; ++j) {
                sc8[cb][j] = (HALF)lscbi[0][c0 + j];
                bi8[cb][j] = (HALF)lscbi[1][c0 + j];
            }
        }
    }

    const int t0 = wv * TPW;

    int   ipf[2][NMT];
    f16x8 apf[2][NMT][2];
#pragma unroll
    for (int p = 0; p < 2; ++p) {
        const int t = t0 + p;
#pragma unroll
        for (int mt = 0; mt < NMT; ++mt) {
            const int v   = nbr[nbo[mt] + (t < 27 ? t : 26)];
            const int idx = (rok[mt] && t < 27) ? v : -1;
            ipf[p][mt] = idx;
            const HALF* pa = h + ((max(idx, 0) << 6) + lq * 8);
            apf[p][mt][0] = *(const f16x8*)(pa);
            apf[p][mt][1] = *(const f16x8*)(pa + 32);
        }
    }

#pragma unroll
    for (int tt = 0; tt < TPW; ++tt) {
        const int t = t0 + tt;
        if (t >= 27) break;                       // wave-uniform (wave3 tail)
        const int cur = tt & 1;

        f16x8 a0[NMT], a1[NMT]; int im[NMT];
#pragma unroll
        for (int mt = 0; mt < NMT; ++mt) {
            a0[mt] = apf[cur][mt][0]; a1[mt] = apf[cur][mt][1]; im[mt] = ipf[cur][mt];
        }

        if (tt + 2 < TPW && t + 2 < 27) {
#pragma unroll
            for (int mt = 0; mt < NMT; ++mt) {
                const int v   = nbr[nbo[mt] + t + 2];
                const int idx = rok[mt] ? v : -1;
                ipf[cur][mt] = idx;
                const HALF* pa = h + ((max(idx, 0) << 6) + lq * 8);
                apf[cur][mt][0] = *(const f16x8*)(pa);
                apf[cur][mt][1] = *(const f16x8*)(pa + 32);
            }
        }

        const HALF* wb = Wt + (size_t)(2 * t) * (CO_PAD * 32) + lq * 8;
        f16x8 b0[NJB], b1[NJB];
#pragma unroll
        for (int jb = 0; jb < NJB; ++jb) {
            b0[jb] = *(const f16x8*)(wb + (size_t)(jb * 16 + l15) * 32);
            b1[jb] = *(const f16x8*)(wb + CO_PAD * 32 + (size_t)(jb * 16 + l15) * 32);
        }

#pragma unroll
        for (int mt = 0; mt < NMT; ++mt) {
            f16x8 a = a0[mt];
            if constexpr (FUSED) {
                a = a * sc8[0] + bi8[0];
#pragma unroll
                for (int j = 0; j < 8; ++j) a[j] = (a[j] < (HALF)0.f) ? (HALF)0.f : a[j];
            }
            const int m = ~(im[mt] >> 31);
            i32x4 ai = __builtin_bit_cast(i32x4, a);
            ai.x &= m; ai.y &= m; ai.z &= m; ai.w &= m;
            a = __builtin_bit_cast(f16x8, ai);
#pragma unroll
            for (int jb = 0; jb < NJB; ++jb)
                acc[mt][jb] = __builtin_amdgcn_mfma_f32_16x16x32_f16(a, b0[jb], acc[mt][jb], 0, 0, 0);
        }
#pragma unroll
        for (int mt = 0; mt < NMT; ++mt) {
            f16x8 a = a1[mt];
            if constexpr (FUSED) {
                a = a * sc8[1] + bi8[1];
#pragma unroll
                for (int j = 0; j < 8; ++j) a[j] = (a[j] < (HALF)0.f) ? (HALF)0.f : a[j];
            }
            const int m = ~(im[mt] >> 31);
            i32x4 ai = __builtin_bit_cast(i32x4, a);
            ai.x &= m; ai.y &= m; ai.z &= m; ai.w &= m;
            a = __builtin_bit_cast(f16x8, ai);
#pragma unroll
            for (int jb = 0; jb < NJB; ++jb)
                acc[mt][jb] = __builtin_amdgcn_mfma_f32_16x16x32_f16(a, b1[jb], acc[mt][jb], 0, 0, 0);
        }
    }

    // ---- cross-wave tree reduction (3 syncs)
    if (wv & 1) {
#pragma unroll
        for (int mt = 0; mt < NMT; ++mt)
#pragma unroll
            for (int jb = 0; jb < NJB; ++jb)
                lred[wv >> 1][(mt * NJB + jb) * 64 + lane] = acc[mt][jb];
    }
    __syncthreads();
    if (!(wv & 1)) {
#pragma unroll
        for (int mt = 0; mt < NMT; ++mt)
#pragma unroll
            for (int jb = 0; jb < NJB; ++jb)
                acc[mt][jb] += lred[wv >> 1][(mt * NJB + jb) * 64 + lane];
    }
    __syncthreads();
    if (wv == 2) {
#pragma unroll
        for (int mt = 0; mt < NMT; ++mt)
#pragma unroll
            for (int jb = 0; jb < NJB; ++jb)
                lred[0][(mt * NJB + jb) * 64 + lane] = acc[mt][jb];
    }
    __syncthreads();

    if (wv == 0) {
#pragma unroll
        for (int mt = 0; mt < NMT; ++mt)
#pragma unroll
            for (int jb = 0; jb < NJB; ++jb)
                acc[mt][jb] += lred[0][(mt * NJB + jb) * 64 + lane];

        float* sl = sums + (bid & 7) * 128;
#pragma unroll
        for (int jb = 0; jb < NJB; ++jb) {
            const int col = jb * 16 + l15;
            float s = 0.f, sq = 0.f;
#pragma unroll
            for (int mt = 0; mt < NMT; ++mt) {
                const int rb = rowBase + mt * 16 + lq * 4;
#pragma unroll
                for (int r = 0; r < 4; ++r) {
                    if (rb + r < n) {
                        const float v = acc[mt][jb][r];
                        yout[(size_t)(rb + r) * CO_PAD + col] = (HALF)v;
                        s += v;
                        sq += v * v;
                    }
                }
            }
            s  += __shfl_xor(s, 16);  s  += __shfl_xor(s, 32);
            sq += __shfl_xor(sq, 16); sq += __shfl_xor(sq, 32);
            if (lane < 16) {
                atomicAdd(&sl[col], s);
                atomicAdd(&sl[CO_PAD + col], sq);
            }
        }
    }
}

// ================= conv_dyn: compact-active-tap kernel (sparse layers) =================
// R12's dynamic path only (no static branch -> no regalloc coupling). Voxel
// sparsity makes most taps all-invalid per 32-row block (exact-zero masked) ->
// skip them. Used for i3/m2/i2/m1/c5.
template<int CI, int CO_PAD, bool FUSED>
__global__ __launch_bounds__(256, 2) void conv_dyn(
    const HALF* __restrict__ h, const int* __restrict__ nbr,
    const HALF* __restrict__ Wt, HALF* __restrict__ yout,
    float* __restrict__ sums, int n,
    const float* __restrict__ psums, const float* __restrict__ pg,
    const float* __restrict__ pb, float pinvn)
{
    constexpr int NMT   = 2;
    constexpr int NJB   = CO_PAD / 16;
    constexpr int NCB   = (CI >= 64) ? 2 : 1;
    constexpr int ROWS  = 32;
    constexpr int PAIRS = NMT * NJB;

    __shared__ f32x4 lred[2][PAIRS * 64];
    __shared__ float lscbi[2][64];
    __shared__ int   lidx[ROWS * 27];
    __shared__ int   tflag[27];
    __shared__ int   tls[32];
    __shared__ int   ntapS;

    const int wv   = threadIdx.x >> 6;
    const int lane = threadIdx.x & 63;
    const int l15  = lane & 15;
    const int lq   = lane >> 4;

    int bid = blockIdx.x;
    {
        const int nwg = gridDim.x;
        const int q = nwg >> 3, r = nwg & 7;
        const int xcd = bid & 7, idx = bid >> 3;
        bid = (xcd < r ? xcd * (q + 1) : r * (q + 1) + (xcd - r) * q) + idx;
    }
    const int rowBase = bid * ROWS;

    for (int i = threadIdx.x; i < ROWS * 27; i += 256) {
        const int r   = i / 27;
        const int row = rowBase + r;
        lidx[i] = (row < n) ? nbr[(size_t)row * 27 + (i - r * 27)] : -1;
    }
    if constexpr (FUSED) {
        const int c = threadIdx.x;
        if (c < CI) {
            float s = 0.f, q = 0.f;
#pragma unroll
            for (int k = 0; k < 8; ++k) { s += psums[k * 128 + c]; q += psums[k * 128 + CI + c]; }
            const float mu  = s * pinvn;
            const float var = q * pinvn - mu * mu;
            const float sc  = rsqrtf(var + 1e-3f) * pg[c];
            lscbi[0][c] = sc;
            lscbi[1][c] = pb[c] - mu * sc;
        }
    }
    __syncthreads();

    if (threadIdx.x < 27) {
        int any = 0;
        for (int r = 0; r < ROWS; ++r) any |= ~(lidx[r * 27 + threadIdx.x] >> 31);
        tflag[threadIdx.x] = any & 1;
    }
    __syncthreads();
    if (threadIdx.x == 0) {
        int c = 0;
#pragma unroll
        for (int t = 0; t < 27; ++t) if (tflag[t]) tls[c++] = t;
        ntapS = c;
        for (int t = c; t < 32; ++t) tls[t] = 27;  // sentinel pad
    }
    __syncthreads();
    const int NT = ntapS;

    f16x8 sc8[NCB], bi8[NCB];
    if constexpr (FUSED) {
#pragma unroll
        for (int cb = 0; cb < NCB; ++cb) {
            const int c0 = cb * 32 + ((lq * 8) & (CI - 1));
#pragma unroll
            for (int j = 0; j < 8; ++j) {
                sc8[cb][j] = (HALF)lscbi[0][c0 + j];
                bi8[cb][j] = (HALF)lscbi[1][c0 + j];
            }
        }
    }

    f32x4 acc[NMT][NJB];
#pragma unroll
    for (int mt = 0; mt < NMT; ++mt)
#pragma unroll
        for (int jb = 0; jb < NJB; ++jb)
#pragma unroll
            for (int r = 0; r < 4; ++r) acc[mt][jb][r] = 0.f;

    int lb[NMT];
#pragma unroll
    for (int mt = 0; mt < NMT; ++mt) lb[mt] = (mt * 16 + l15) * 27;

    #define CONSUME(aV_, imV_, bV_, CBIDX_) do { \
        f16x8 a_ = (aV_); \
        if constexpr (FUSED) { \
            a_ = a_ * sc8[CBIDX_] + bi8[CBIDX_]; \
            _Pragma("unroll") \
            for (int j_ = 0; j_ < 8; ++j_) a_[j_] = (a_[j_] < (HALF)0.f) ? (HALF)0.f : a_[j_]; \
        } \
        const int m_ = ~((imV_) >> 31); \
        i32x4 ai_ = __builtin_bit_cast(i32x4, a_); \
        ai_.x &= m_; ai_.y &= m_; ai_.z &= m_; ai_.w &= m_; \
        a_ = __builtin_bit_cast(f16x8, ai_); \
        _Pragma("unroll") \
        for (int jb_ = 0; jb_ < NJB; ++jb_) \
            acc[mt][jb_] = __builtin_amdgcn_mfma_f32_16x16x32_f16(a_, (bV_)[jb_], acc[mt][jb_], 0, 0, 0); \
    } while (0)

    if constexpr (CI == 64) {
        int ti = wv;
        int   tcur, icur[NMT];
        f16x8 a0c[NMT], a1c[NMT];
        {
            tcur = tls[ti];
#pragma unroll
            for (int mt = 0; mt < NMT; ++mt) {
                const int idx = (tcur < 27) ? lidx[lb[mt] + min(tcur, 26)] : -1;
                icur[mt] = idx;
                const HALF* pa = h + ((max(idx, 0) << 6) + lq * 8);
                a0c[mt] = *(const f16x8*)(pa);
                a1c[mt] = *(const f16x8*)(pa + 32);
            }
        }
        for (; ti < NT; ti += 4) {
            int   tnx = tls[min(ti + 4, 31)];
            int   inx[NMT];
            f16x8 a0n[NMT], a1n[NMT];
#pragma unroll
            for (int mt = 0; mt < NMT; ++mt) {
                const int idx = (tnx < 27) ? lidx[lb[mt] + min(tnx, 26)] : -1;
                inx[mt] = idx;
                const HALF* pa = h + ((max(idx, 0) << 6) + lq * 8);
                a0n[mt] = *(const f16x8*)(pa);
                a1n[mt] = *(const f16x8*)(pa + 32);
            }

            const HALF* wb = Wt + (size_t)(2 * tcur) * (CO_PAD * 32) + lq * 8;
            f16x8 b0[NJB], b1[NJB];
#pragma unroll
            for (int jb = 0; jb < NJB; ++jb) {
                b0[jb] = *(const f16x8*)(wb + (size_t)(jb * 16 + l15) * 32);
                b1[jb] = *(const f16x8*)(wb + CO_PAD * 32 + (size_t)(jb * 16 + l15) * 32);
            }

#pragma unroll
            for (int mt = 0; mt < NMT; ++mt) CONSUME(a0c[mt], icur[mt], b0, 0);
#pragma unroll
            for (int mt = 0; mt < NMT; ++mt) CONSUME(a1c[mt], icur[mt], b1, NCB - 1);

            tcur = tnx;
#pragma unroll
            for (int mt = 0; mt < NMT; ++mt) {
                icur[mt] = inx[mt]; a0c[mt] = a0n[mt]; a1c[mt] = a1n[mt];
            }
        }
    } else if constexpr (CI == 32) {
        int ti = wv;
        int   tcur, icur[NMT];
        f16x8 ac[NMT];
        {
            tcur = tls[ti];
#pragma unroll
            for (int mt = 0; mt < NMT; ++mt) {
                const int idx = (tcur < 27) ? lidx[lb[mt] + min(tcur, 26)] : -1;
                icur[mt] = idx;
                ac[mt] = *(const f16x8*)(h + ((max(idx, 0) << 5) + lq * 8));
            }
        }
        for (; ti < NT; ti += 4) {
            int   tnx = tls[min(ti + 4, 31)];
            int   inx[NMT];
            f16x8 an[NMT];
#pragma unroll
            for (int mt = 0; mt < NMT; ++mt) {
                const int idx = (tnx < 27) ? lidx[lb[mt] + min(tnx, 26)] : -1;
                inx[mt] = idx;
                an[mt] = *(const f16x8*)(h + ((max(idx, 0) << 5) + lq * 8));
            }

            const HALF* wb = Wt + (size_t)tcur * (CO_PAD * 32) + lq * 8;
            f16x8 b[NJB];
#pragma unroll
            for (int jb = 0; jb < NJB; ++jb)
                b[jb] = *(const f16x8*)(wb + (size_t)(jb * 16 + l15) * 32);

#pragma unroll
            for (int mt = 0; mt < NMT; ++mt) CONSUME(ac[mt], icur[mt], b, 0);

            tcur = tnx;
#pragma unroll
            for (int mt = 0; mt < NMT; ++mt) { icur[mt] = inx[mt]; ac[mt] = an[mt]; }
        }
    } else {
        // CI == 16: two list entries per MFMA step (lq>>1 selects); sentinel masked
        const int NS = (NT + 1) >> 1;
        int ti = wv;
        int   tcur, icur[NMT];
        f16x8 ac[NMT];
        {
            tcur = tls[min(2 * ti + (lq >> 1), 31)];
#pragma unroll
            for (int mt = 0; mt < NMT; ++mt) {
                const int idx = (tcur < 27) ? lidx[lb[mt] + min(tcur, 26)] : -1;
                icur[mt] = idx;
                ac[mt] = *(const f16x8*)(h + ((max(idx, 0) << 4) + (lq & 1) * 8));
            }
        }
        for (; ti < NS; ti += 4) {
            int   tnx = tls[min(2 * (ti + 4) + (lq >> 1), 31)];
            int   inx[NMT];
            f16x8 an[NMT];
#pragma unroll
            for (int mt = 0; mt < NMT; ++mt) {
                const int idx = (tnx < 27) ? lidx[lb[mt] + min(tnx, 26)] : -1;
                inx[mt] = idx;
                an[mt] = *(const f16x8*)(h + ((max(idx, 0) << 4) + (lq & 1) * 8));
            }

            const int tb = min(tcur, 26);
            f16x8 b[NJB];
#pragma unroll
            for (int jb = 0; jb < NJB; ++jb)
                b[jb] = *(const f16x8*)(Wt + (size_t)(tb >> 1) * (CO_PAD * 32)
                                        + (size_t)(jb * 16 + l15) * 32 + (tb & 1) * 16 + (lq & 1) * 8);

#pragma unroll
            for (int mt = 0; mt < NMT; ++mt) CONSUME(ac[mt], icur[mt], b, 0);

            tcur = tnx;
#pragma unroll
            for (int mt = 0; mt < NMT; ++mt) { icur[mt] = inx[mt]; ac[mt] = an[mt]; }
        }
    }
    #undef CONSUME

    // ---- cross-wave tree reduction (3 syncs)
    if (wv & 1) {
#pragma unroll
        for (int mt = 0; mt < NMT; ++mt)
#pragma unroll
            for (int jb = 0; jb < NJB; ++jb)
                lred[wv >> 1][(mt * NJB + jb) * 64 + lane] = acc[mt][jb];
    }
    __syncthreads();
    if (!(wv & 1)) {
#pragma unroll
        for (int mt = 0; mt < NMT; ++mt)
#pragma unroll
            for (int jb = 0; jb < NJB; ++jb)
                acc[mt][jb] += lred[wv >> 1][(mt * NJB + jb) * 64 + lane];
    }
    __syncthreads();
    if (wv == 2) {
#pragma unroll
        for (int mt = 0; mt < NMT; ++mt)
#pragma unroll
            for (int jb = 0; jb < NJB; ++jb)
                lred[0][(mt * NJB + jb) * 64 + lane] = acc[mt][jb];
    }
    __syncthreads();

    if (wv == 0) {
#pragma unroll
        for (int mt = 0; mt < NMT; ++mt)
#pragma unroll
            for (int jb = 0; jb < NJB; ++jb)
                acc[mt][jb] += lred[0][(mt * NJB + jb) * 64 + lane];

        float* sl = sums + (bid & 7) * 128;
#pragma unroll
        for (int jb = 0; jb < NJB; ++jb) {
            const int col = jb * 16 + l15;
            float s = 0.f, sq = 0.f;
#pragma unroll
            for (int mt = 0; mt < NMT; ++mt) {
                const int rb = rowBase + mt * 16 + lq * 4;
#pragma unroll
                for (int r = 0; r < 4; ++r) {
                    if (rb + r < n) {
                        const float v = acc[mt][jb][r];
                        yout[(size_t)(rb + r) * CO_PAD + col] = (HALF)v;
                        s += v;
                        sq += v * v;
                    }
                }
            }
            s  += __shfl_xor(s, 16);  s  += __shfl_xor(s, 32);
            sq += __shfl_xor(sq, 16); sq += __shfl_xor(sq, 32);
            if (lane < 16) {
                atomicAdd(&sl[col], s);
                atomicAdd(&sl[CO_PAD + col], sq);
            }
        }
    }
}

// ---- final: normalize (no relu), co=3 out of CO_PAD=16, fp32 output; striped sums
__global__ void bn_out_kernel(const HALF* __restrict__ y, const float* __restrict__ sums,
                              const float* __restrict__ g, const float* __restrict__ b,
                              int n, float invn, float* __restrict__ out)
{
    int i = blockIdx.x * 256 + threadIdx.x;
    if (i >= n * 3) return;
    int row = i / 3;
    int c = i - row * 3;
    float ssum = 0.f, qsum = 0.f;
#pragma unroll
    for (int k2 = 0; k2 < 8; ++k2) {
        ssum += sums[k2 * 128 + c];
        qsum += sums[k2 * 128 + 16 + c];
    }
    float mu  = ssum * invn;
    float var = qsum * invn - mu * mu;
    float sc  = rsqrtf(var + 1e-3f) * g[c];
    out[i] = ((float)y[(size_t)row * 16 + c] - mu) * sc + b[c];
}

extern "C" void kernel_launch(void* const* d_in, const int* in_sizes, int n_in,
                              void* d_out, int out_size, void* d_ws, size_t ws_size,
                              hipStream_t stream)
{
    const int* nbr4  = (const int*)d_in[0];
    const int* inv43 = (const int*)d_in[1];
    const int* nbr3  = (const int*)d_in[2];
    const int* inv32 = (const int*)d_in[3];
    const int* nbr2  = (const int*)d_in[4];
    const int* inv21 = (const int*)d_in[5];
    const int* nbr1  = (const int*)d_in[6];
    const float* x   = (const float*)d_in[7];

    const int n4 = in_sizes[0] / 27;
    const int n3 = in_sizes[1] / 27;
    const int n2 = in_sizes[3] / 27;
    const int n1 = in_sizes[5] / 27;

    // specs: m4,i4,m3,i3,m2,i2,m1,c5
    const int CIs[8]  = {64, 64, 64, 64, 32, 32, 16, 16};
    const int COPs[8] = {64, 64, 64, 32, 32, 16, 16, 16};
    int KPs[8], wtoff[8];
    int wtot = 0;
    for (int s = 0; s < 8; ++s) {
        KPs[s] = ((27 * CIs[s] + 31) / 32) * 32;
        wtoff[s] = wtot;
        wtot += COPs[s] * KPs[s];
    }

    char* ws = (char*)d_ws;
    HALF* wt = (HALF*)ws;
    size_t off = ((size_t)wtot * sizeof(HALF) + 255) & ~(size_t)255;
    float* sums = (float*)(ws + off);
    off += 8 * 1024 * sizeof(float);              // 8 layers x 8 stripes x 128 floats
    off = (off + 255) & ~(size_t)255;
    HALF* xh = (HALF*)(ws + off);
    off += ((size_t)n4 * 64 * sizeof(HALF) + 255) & ~(size_t)255;
    size_t bufElems = 0;
    {
        size_t cand[4] = {(size_t)n4 * 64, (size_t)n3 * 64, (size_t)n2 * 32, (size_t)n1 * 16};
        for (int i = 0; i < 4; ++i) if (cand[i] > bufElems) bufElems = cand[i];
    }
    HALF* Y0 = (HALF*)(ws + off);
    off += (bufElems * sizeof(HALF) + 255) & ~(size_t)255;
    HALF* Y1 = (HALF*)(ws + off);

    hipMemsetAsync(sums, 0, 8 * 1024 * sizeof(float), stream);

    WArgs wa;
    for (int s = 0; s < 8; ++s) { wa.W[s] = (const float*)d_in[8 + 3 * s]; wa.dst[s] = wt + wtoff[s]; }
    {
        int maxTotal = 64 * KPs[0];
        dim3 grid((maxTotal + 255) / 256, 8);
        convert_all_w_kernel<<<grid, 256, 0, stream>>>(wa);
    }
    convert_x_kernel<<<(n4 * 64 + 255) / 256, 256, 0, stream>>>(x, xh, n4 * 64);

#define G(s) ((const float*)d_in[9 + 3 * (s)])
#define B(s) ((const float*)d_in[10 + 3 * (s)])
#define SUMS(s) (sums + (s) * 1024)
#define GRID(nn) (((nn) + 31) / 32)

    // m4: xh(n4,64) -> Y0 (raw)  [static: tap union always 27-dense enough]
    conv_static<64, false><<<GRID(n4), 256, 0, stream>>>(
        xh, nbr4, wt + wtoff[0], Y0, SUMS(0), n4, nullptr, nullptr, nullptr, 0.f);
    // i4: norm(m4) fused; Y0(n4) -> Y1(n3)  [static]
    conv_static<64, true><<<GRID(n3), 256, 0, stream>>>(
        Y0, inv43, wt + wtoff[1], Y1, SUMS(1), n3, SUMS(0), G(0), B(0), 1.f / n4);
    // m3: norm(i4) fused; Y1 -> Y0  [static]
    conv_static<64, true><<<GRID(n3), 256, 0, stream>>>(
        Y1, nbr3, wt + wtoff[2], Y0, SUMS(2), n3, SUMS(1), G(1), B(1), 1.f / n3);
    // i3: norm(m3) fused; Y0(n3) -> Y1(n2), co 32  [dynamic]
    conv_dyn<64, 32, true><<<GRID(n2), 256, 0, stream>>>(
        Y0, inv32, wt + wtoff[3], Y1, SUMS(3), n2, SUMS(2), G(2), B(2), 1.f / n3);
    // m2: norm(i3) fused; Y1 -> Y0  [dynamic]
    conv_dyn<32, 32, true><<<GRID(n2), 256, 0, stream>>>(
        Y1, nbr2, wt + wtoff[4], Y0, SUMS(4), n2, SUMS(3), G(3), B(3), 1.f / n2);
    // i2: norm(m2) fused; Y0(n2) -> Y1(n1), co 16  [dynamic]
    conv_dyn<32, 16, true><<<GRID(n1), 256, 0, stream>>>(
        Y0, inv21, wt + wtoff[5], Y1, SUMS(5), n1, SUMS(4), G(4), B(4), 1.f / n2);
    // m1: norm(i2) fused; Y1 -> Y0  [dynamic]
    conv_dyn<16, 16, true><<<GRID(n1), 256, 0, stream>>>(
        Y1, nbr1, wt + wtoff[6], Y0, SUMS(6), n1, SUMS(5), G(5), B(5), 1.f / n1);
    // c5: norm(m1) fused; Y0 -> Y1 (raw), then fp32 out  [dynamic]
    conv_dyn<16, 16, true><<<GRID(n1), 256, 0, stream>>>(
        Y0, nbr1, wt + wtoff[7], Y1, SUMS(7), n1, SUMS(6), G(6), B(6), 1.f / n1);
    bn_out_kernel<<<(n1 * 3 + 255) / 256, 256, 0, stream>>>(
        Y1, SUMS(7), G(7), B(7), n1, 1.f / n1, (float*)d_out);

#undef G
#undef B
#undef SUMS
#undef GRID
}